// Round 10
// baseline (345.210 us; speedup 1.0000x reference)
//
#include <hip/hip_runtime.h>
#include <math.h>

// ---------------------------------------------------------------------------
// TransformerBlock: B=2, T=2048, D=1024, H=16, HD=64, pre-LN, causal attn, GELU
// Round 15 (base = round 14, 338.3us): W2 split-K=2 inside the proven gemmw
// loop. Evidence: W1 (3 blk/CU, same FLOPs, same loop) < 60.4us vs W2
// (2 blk/CU, grid-capped) = 61us; m97's 874TF was this family at 3 blk/CU.
// Grid (32,16,2) = 1024 blocks -> 3 blk/CU (48KB LDS cap). z=0: fp32 out +
// bias + residual (K first half); z=1: f16 partial (no bias) into the dead
// W1^T workspace region (rewritten by prep each replay); redux folds it.
// No atomics, no memsets. Everything else = r14 verbatim.
// ---------------------------------------------------------------------------

typedef _Float16 half8 __attribute__((ext_vector_type(8)));
typedef _Float16 half4v __attribute__((ext_vector_type(4)));
typedef float floatx4 __attribute__((ext_vector_type(4)));

#define DMODEL 1024
#define SEQT   2048
#define NTOK   4096   // B*T
#define NHEAD  16
#define HDIM   64

// Async global->LDS, 16B/lane. LDS dest = wave-uniform base + lane*16 [m104].
__device__ __forceinline__ void llds16(const _Float16* g, _Float16* l) {
  __builtin_amdgcn_global_load_lds(
      (const __attribute__((address_space(1))) void*)g,
      (__attribute__((address_space(3))) void*)l, 16, 0, 0);
}

// ---------------------------------------------------------------------------
// prep_kernel: blocks [0,4096) = LayerNorm1 rows; blocks [4096,7168) =
// weight convert+transpose on 64x64 tiles with vectorized f16 writes.
// wt layout (elements): Wq^T @0, Wk^T @1M, Wv^T @2M, Wo^T @3M,
//                       W1^T @4M (4096x1024), W2^T @8M (1024x4096).
// ---------------------------------------------------------------------------
__global__ __launch_bounds__(256) void prep_kernel(
    const float* __restrict__ x, const float* __restrict__ g,
    const float* __restrict__ b, _Float16* __restrict__ h16out,
    const float* __restrict__ Wq, const float* __restrict__ Wk,
    const float* __restrict__ Wv, const float* __restrict__ Wo,
    const float* __restrict__ W1, const float* __restrict__ W2,
    _Float16* __restrict__ wt_base) {
  const int t256 = threadIdx.x;
  if (blockIdx.x < 4096) {
    // ---- LayerNorm (row = blockIdx.x) ----
    int row = blockIdx.x;
    const float4 xv = ((const float4*)(x + (size_t)row * DMODEL))[t256];
    float s = xv.x + xv.y + xv.z + xv.w;
    float s2 = xv.x * xv.x + xv.y * xv.y + xv.z * xv.z + xv.w * xv.w;
#pragma unroll
    for (int off = 32; off; off >>= 1) {
      s += __shfl_down(s, off);
      s2 += __shfl_down(s2, off);
    }
    __shared__ float red[8];
    int wid = t256 >> 6;
    if ((t256 & 63) == 0) { red[wid] = s; red[wid + 4] = s2; }
    __syncthreads();
    s = red[0] + red[1] + red[2] + red[3];
    s2 = red[4] + red[5] + red[6] + red[7];
    float mu = s * (1.0f / DMODEL);
    float var = s2 * (1.0f / DMODEL) - mu * mu;
    float rstd = rsqrtf(var + 1e-5f);
    const float4 gv = ((const float4*)g)[t256];
    const float4 bv = ((const float4*)b)[t256];
    half4v o;
    o[0] = (_Float16)((xv.x - mu) * rstd * gv.x + bv.x);
    o[1] = (_Float16)((xv.y - mu) * rstd * gv.y + bv.y);
    o[2] = (_Float16)((xv.z - mu) * rstd * gv.z + bv.z);
    o[3] = (_Float16)((xv.w - mu) * rstd * gv.w + bv.w);
    *(half4v*)(h16out + (size_t)row * DMODEL + t256 * 4) = o;
    return;
  }
  // ---- weight transpose, 64x64 fp32 tile -> f16 [N][K] ----
  __shared__ float lb[64][65];
  int id = blockIdx.x - 4096;
  const float* src; _Float16* dst; int K, N, t;
  if (id < 1024) {
    int s = id >> 8;
    src = (s == 0) ? Wq : (s == 1) ? Wk : (s == 2) ? Wv : Wo;
    dst = wt_base + (size_t)s * (1024 * 1024);
    K = 1024; N = 1024; t = id & 255;
  } else if (id < 2048) {
    src = W1; dst = wt_base + (size_t)4 * 1024 * 1024; K = 1024; N = 4096; t = id - 1024;
  } else {
    src = W2; dst = wt_base + (size_t)8 * 1024 * 1024; K = 4096; N = 1024; t = id - 2048;
  }
  int tilesN = N >> 6;
  int tk = t / tilesN, tn = t % tilesN;
#pragma unroll
  for (int i = 0; i < 4; ++i) {
    int row = i * 16 + (t256 >> 4);
    int c4 = (t256 & 15) * 4;
    float4 v = *(const float4*)&src[(size_t)(tk * 64 + row) * N + tn * 64 + c4];
    lb[row][c4] = v.x; lb[row][c4 + 1] = v.y;
    lb[row][c4 + 2] = v.z; lb[row][c4 + 3] = v.w;
  }
  __syncthreads();
  {
    int r = t256 >> 2, cb = t256 & 3;
    half8 h0, h1;
#pragma unroll
    for (int kk = 0; kk < 8; ++kk) h0[kk] = (_Float16)lb[cb * 16 + kk][r];
#pragma unroll
    for (int kk = 0; kk < 8; ++kk) h1[kk] = (_Float16)lb[cb * 16 + 8 + kk][r];
    _Float16* dp = dst + (size_t)(tn * 64 + r) * K + tk * 64 + cb * 16;
    *(half8*)dp = h0;
    *(half8*)(dp + 8) = h1;
  }
}

// ---------------------------------------------------------------------------
// LayerNorm (standalone, for LN2): fp32 in -> f16 out. One row per block.
// ---------------------------------------------------------------------------
__global__ __launch_bounds__(256) void ln_kernel(
    const float* __restrict__ x, const float* __restrict__ g,
    const float* __restrict__ b, _Float16* __restrict__ out) {
  int row = blockIdx.x;
  int t = threadIdx.x;
  const float4 xv = ((const float4*)(x + (size_t)row * DMODEL))[t];
  float s = xv.x + xv.y + xv.z + xv.w;
  float s2 = xv.x * xv.x + xv.y * xv.y + xv.z * xv.z + xv.w * xv.w;
#pragma unroll
  for (int off = 32; off; off >>= 1) {
    s += __shfl_down(s, off);
    s2 += __shfl_down(s2, off);
  }
  __shared__ float red[8];
  int wid = t >> 6;
  if ((t & 63) == 0) { red[wid] = s; red[wid + 4] = s2; }
  __syncthreads();
  s = red[0] + red[1] + red[2] + red[3];
  s2 = red[4] + red[5] + red[6] + red[7];
  float mu = s * (1.0f / DMODEL);
  float var = s2 * (1.0f / DMODEL) - mu * mu;
  float rstd = rsqrtf(var + 1e-5f);
  const float4 gv = ((const float4*)g)[t];
  const float4 bv = ((const float4*)b)[t];
  half4v o;
  o[0] = (_Float16)((xv.x - mu) * rstd * gv.x + bv.x);
  o[1] = (_Float16)((xv.y - mu) * rstd * gv.y + bv.y);
  o[2] = (_Float16)((xv.z - mu) * rstd * gv.z + bv.z);
  o[3] = (_Float16)((xv.w - mu) * rstd * gv.w + bv.w);
  *(half4v*)(out + (size_t)row * DMODEL + t * 4) = o;
}

// ---------------------------------------------------------------------------
// Split-K reduce: out += p1 (f16 partial). 4 floats/thread, fully coalesced.
// ---------------------------------------------------------------------------
__global__ __launch_bounds__(256) void redux_kernel(
    float* __restrict__ out, const _Float16* __restrict__ p1) {
  size_t i = ((size_t)blockIdx.x * 256 + threadIdx.x) * 4;
  float4 o = *(float4*)(out + i);
  half4v a = *(const half4v*)(p1 + i);
  o.x += (float)a[0];
  o.y += (float)a[1];
  o.z += (float)a[2];
  o.w += (float)a[3];
  *(float4*)(out + i) = o;
}

// ---------------------------------------------------------------------------
// gemmw_kernel: C[4096,N] = A @ Bt^T, 128x64 tile, BK=64, 4 waves.
// dbuf + single-__syncthreads (r9-proven sync structure, r12/r14-proven at
// BK=64). Swizzle: row = 64 f16 = 8 chunks of 16B; LDS slot s of row r holds
// global chunk s ^ (r&7) (pre-swizzled source, linear LDS dest per m104).
// Fragment read of global chunk G=(kh*4+q8) of row r uses slot G ^ (r&7).
// Bank math: 16 lanes -> 8 slots x 2 lanes = 2-way (free, m136).
// OUTMODE 0: bias + residual(fp32); fp32 out, row stride 1024 (Wo).
// OUTMODE 1: bias + fast GELU; f16 out, row stride 4096 (W1).
// OUTMODE 2: QKV fused: sel = blockIdx.y>>4 picks {Wq,Wk,Wv}; q,k scatter
//            [B,H,T,HD]; v scatters TRANSPOSED [B,H,HD,T] with half4 pack.
// OUTMODE 3: split-K=2 via blockIdx.z (W2). z=0: K first half, fp32 out +
//            bias + res. z=1: K second half, f16 partial (no bias) to outh.
// ---------------------------------------------------------------------------
template <int OUTMODE>
__global__ __launch_bounds__(256) void gemmw_kernel(
    const _Float16* __restrict__ A, const _Float16* __restrict__ Bt0, int K,
    const float* __restrict__ bias0, const float* __restrict__ bias1,
    const float* __restrict__ bias2, const float* __restrict__ res,
    float* __restrict__ outf, _Float16* __restrict__ outh) {
  __shared__ __align__(16) _Float16 As[2][128 * 64];
  __shared__ __align__(16) _Float16 Bs[2][64 * 64];
  const int tid = threadIdx.x;
  const int m0 = blockIdx.x * 128;
  const int w = tid >> 6, lane = tid & 63;
  const int l15 = lane & 15, q8 = lane >> 4;
  const int wrow = w * 32;
  const _Float16* Bt;
  const float* bias;
  _Float16* outh_sel = outh;
  int n0, sel = 0;
  if (OUTMODE == 2) {
    sel = blockIdx.y >> 4;
    n0 = (blockIdx.y & 15) * 64;
    Bt = Bt0 + (size_t)sel * (1024 * 1024);
    bias = (sel == 0) ? bias0 : (sel == 1) ? bias1 : bias2;
    outh_sel = outh + (size_t)sel * ((size_t)NTOK * DMODEL);
  } else {
    n0 = blockIdx.y * 64;
    Bt = Bt0;
    bias = bias0;
  }
  int Keff = K, koff = 0;
  if (OUTMODE == 3) { Keff = K >> 1; koff = blockIdx.z * Keff; }

  const _Float16* gA[4]; int la[4];
  const _Float16* gB[2]; int lb2[2];
#pragma unroll
  for (int i = 0; i < 4; ++i) {
    int c = i * 256 + tid;
    int r = c >> 3, gc = ((c & 7) ^ (r & 7)) * 8;
    gA[i] = A + (size_t)(m0 + r) * K + koff + gc;
    la[i] = c * 8;
  }
#pragma unroll
  for (int i = 0; i < 2; ++i) {
    int c = i * 256 + tid;
    int r = c >> 3, gc = ((c & 7) ^ (r & 7)) * 8;
    gB[i] = Bt + (size_t)(n0 + r) * K + koff + gc;
    lb2[i] = c * 8;
  }
  auto stage = [&](int buf) {
#pragma unroll
    for (int i = 0; i < 4; ++i) {
      llds16(gA[i], &As[buf][la[i]]);
      gA[i] += 64;
    }
#pragma unroll
    for (int i = 0; i < 2; ++i) {
      llds16(gB[i], &Bs[buf][lb2[i]]);
      gB[i] += 64;
    }
  };

  floatx4 acc[2][4];
#pragma unroll
  for (int i = 0; i < 2; ++i)
#pragma unroll
    for (int j = 0; j < 4; ++j) acc[i][j] = (floatx4){0.f, 0.f, 0.f, 0.f};

  const int nk = Keff >> 6;
  stage(0);
  __syncthreads();
  for (int t = 0; t < nk; ++t) {
    const int buf = t & 1;
    if (t + 1 < nk) stage(buf ^ 1);  // async, in flight during compute
    half8 af[2][2], bf[4][2];
#pragma unroll
    for (int i = 0; i < 2; ++i) {
      int rA = wrow + i * 16 + l15;
#pragma unroll
      for (int kh = 0; kh < 2; ++kh) {
        int sl = ((kh * 4 + q8) ^ (rA & 7)) * 8;
        af[i][kh] = *(const half8*)&As[buf][rA * 64 + sl];
      }
    }
#pragma unroll
    for (int j = 0; j < 4; ++j) {
      int rB = j * 16 + l15;
#pragma unroll
      for (int kh = 0; kh < 2; ++kh) {
        int sl = ((kh * 4 + q8) ^ (rB & 7)) * 8;
        bf[j][kh] = *(const half8*)&Bs[buf][rB * 64 + sl];
      }
    }
#pragma unroll
    for (int i = 0; i < 2; ++i)
#pragma unroll
      for (int j = 0; j < 4; ++j) {
        acc[i][j] = __builtin_amdgcn_mfma_f32_16x16x32_f16(af[i][0], bf[j][0], acc[i][j], 0, 0, 0);
        acc[i][j] = __builtin_amdgcn_mfma_f32_16x16x32_f16(af[i][1], bf[j][1], acc[i][j], 0, 0, 0);
      }
    __syncthreads();
  }

  // Epilogue. C/D layout: col = lane&15, row = (lane>>4)*4 + reg   [m89/m91]
#pragma unroll
  for (int i = 0; i < 2; ++i) {
    int rowb = m0 + wrow + i * 16 + q8 * 4;
#pragma unroll
    for (int j = 0; j < 4; ++j) {
      int col = n0 + j * 16 + l15;
      float bval = bias[col];
      if (OUTMODE == 2 && sel == 2) {
        // V transposed [B,H,HD,T]: rows r=0..3 -> tt0..tt0+3 contiguous
        int bb = rowb >> 11, tt0 = rowb & 2047;
        int hh = col >> 6, hd = col & 63;
        half4v hv;
#pragma unroll
        for (int r = 0; r < 4; ++r) hv[r] = (_Float16)(acc[i][j][r] + bval);
        *(half4v*)&outh_sel[((size_t)(bb * NHEAD + hh) * HDIM + hd) * SEQT + tt0] = hv;
      } else {
#pragma unroll
        for (int r = 0; r < 4; ++r) {
          int row = rowb + r;
          float v = acc[i][j][r];
          if (OUTMODE == 0) {
            v += bval + res[(size_t)row * 1024 + col];
            outf[(size_t)row * 1024 + col] = v;
          } else if (OUTMODE == 1) {
            v += bval;
            // fast GELU: v*sigmoid(1.5957691(v + 0.044715 v^3)); |err| < 0.003
            float z = 1.5957691216f * v * (1.0f + 0.044715f * v * v);
            float gl = v / (1.0f + __expf(-z));
            outh[(size_t)row * 4096 + col] = (_Float16)gl;
          } else if (OUTMODE == 2) {
            v += bval;
            int bb = row >> 11, tt = row & 2047;
            int hh = col >> 6, hd = col & 63;
            outh_sel[((size_t)(bb * NHEAD + hh) * SEQT + tt) * HDIM + hd] = (_Float16)v;
          } else {  // OUTMODE 3: split-K
            if (blockIdx.z == 0) {
              v += bval + res[(size_t)row * 1024 + col];
              outf[(size_t)row * 1024 + col] = v;
            } else {
              outh[(size_t)row * 1024 + col] = (_Float16)v;  // partial, no bias
            }
          }
        }
      }
    }
  }
}

// ---------------------------------------------------------------------------
// MFMA flash attention (r10 version: barrier-A is lgkmcnt(0)+s_barrier only).
// ---------------------------------------------------------------------------
__global__ __launch_bounds__(256) void attn_kernel(
    const _Float16* __restrict__ q, const _Float16* __restrict__ k,
    const _Float16* __restrict__ vt, _Float16* __restrict__ ctx) {
  __shared__ __align__(16) _Float16 Ks[2][64 * 64];
  __shared__ __align__(16) _Float16 Vs[2][64 * 64];
  __shared__ __align__(16) _Float16 Ps[64 * 72];
  __shared__ float Lpart[4][64];
  const int tid = threadIdx.x;
  const int w = tid >> 6, lane = tid & 63;
  const int l15 = lane & 15, q8 = lane >> 4;
  const int bh = blockIdx.y;
  const int pr = blockIdx.x;
  const size_t base = (size_t)bh * SEQT * HDIM;

  const _Float16* gk0[2]; const _Float16* gv0[2]; int ldsc[2];
#pragma unroll
  for (int i = 0; i < 2; ++i) {
    int c = i * 256 + w * 64 + lane;
    int r = c >> 3, gc = ((c & 7) ^ (r & 7)) * 8;
    gk0[i] = k + base + (size_t)r * HDIM + gc;
    gv0[i] = vt + base + (size_t)r * SEQT + gc;
    ldsc[i] = c * 8;
  }
  auto stage = [&](int kt, int buf) {
#pragma unroll
    for (int i = 0; i < 2; ++i) {
      llds16(gk0[i] + (size_t)kt * (64 * HDIM), &Ks[buf][ldsc[i]]);
      llds16(gv0[i] + kt * 64, &Vs[buf][ldsc[i]]);
    }
  };

  const int rswA = (l15 & 7);
  const int cs0 = (q8 ^ rswA) * 8;
  const int cs1 = ((4 + q8) ^ rswA) * 8;

  int s = 0;
  stage(0, 0);
  __syncthreads();
  for (int ph = 0; ph < 2; ++ph) {
    const int qtile = ph ? 31 - pr : pr;
    const int ntile = qtile + 1;
    half8 bq[4][2];
#pragma unroll
    for (int nt = 0; nt < 4; ++nt) {
      const half8* qp = (const half8*)(q + base + (size_t)(qtile * 64 + nt * 16 + l15) * HDIM);
      bq[nt][0] = qp[q8];
      bq[nt][1] = qp[4 + q8];
    }
    floatx4 acc[4];
#pragma unroll
    for (int j = 0; j < 4; ++j) acc[j] = (floatx4){0.f, 0.f, 0.f, 0.f};
    float lsum[4] = {0.f, 0.f, 0.f, 0.f};

    for (int jt = 0; jt < ntile; ++jt, ++s) {
      const int buf = s & 1;
      if (s + 1 < 33) {
        int sn = s + 1;
        int nkt = (sn <= pr) ? sn : sn - (pr + 1);
        stage(nkt, buf ^ 1);  // async, in flight during S^T AND PV
      }
      half8 ak0 = *(const half8*)&Ks[buf][(w * 16 + l15) * 64 + cs0];
      half8 ak1 = *(const half8*)&Ks[buf][(w * 16 + l15) * 64 + cs1];
      floatx4 sv[4];
#pragma unroll
      for (int nt = 0; nt < 4; ++nt) {
        sv[nt] = __builtin_amdgcn_mfma_f32_16x16x32_f16(ak0, bq[nt][0],
                                                        (floatx4){0.f, 0.f, 0.f, 0.f}, 0, 0, 0);
        sv[nt] = __builtin_amdgcn_mfma_f32_16x16x32_f16(ak1, bq[nt][1], sv[nt], 0, 0, 0);
      }
      const bool diag = (jt == ntile - 1);
#pragma unroll
      for (int nt = 0; nt < 4; ++nt) {
        half4v phv;
#pragma unroll
        for (int r = 0; r < 4; ++r) {
          float p = __expf(sv[nt][r] * 0.125f);
          if (diag) {
            p = (w * 16 + q8 * 4 + r <= nt * 16 + l15) ? p : 0.f;
          }
          lsum[nt] += p;
          phv[r] = (_Float16)p;
        }
        *(half4v*)&Ps[(nt * 16 + l15) * 72 + w * 16 + q8 * 4] = phv;
      }
      // barrier A: P visible (LDS only); K/V prefetch vmem stays in flight
      asm volatile("s_waitcnt lgkmcnt(0)" ::: "memory");
      __builtin_amdgcn_s_barrier();
      asm volatile("" ::: "memory");
      half8 ap0 = *(const half8*)&Ps[(w * 16 + l15) * 72 + q8 * 8];
      half8 ap1 = *(const half8*)&Ps[(w * 16 + l15) * 72 + 32 + q8 * 8];
#pragma unroll
      for (int ntd = 0; ntd < 4; ++ntd) {
        half8 bv0 = *(const half8*)&Vs[buf][(ntd * 16 + l15) * 64 + cs0];
        half8 bv1 = *(const half8*)&Vs[buf][(ntd * 16 + l15) * 64 + cs1];
        acc[ntd] = __builtin_amdgcn_mfma_f32_16x16x32_f16(ap0, bv0, acc[ntd], 0, 0, 0);
        acc[ntd] = __builtin_amdgcn_mfma_f32_16x16x32_f16(ap1, bv1, acc[ntd], 0, 0, 0);
      }
      __syncthreads();  // barrier B: readers done; prefetch drained
    }

#pragma unroll
    for (int nt = 0; nt < 4; ++nt) {
      lsum[nt] += __shfl_xor(lsum[nt], 16);
      lsum[nt] += __shfl_xor(lsum[nt], 32);
      if (q8 == 0) Lpart[w][nt * 16 + l15] = lsum[nt];
    }
    __syncthreads();
    const int b = bh >> 4, h = bh & 15;
#pragma unroll
    for (int r = 0; r < 4; ++r) {
      int qr = w * 16 + q8 * 4 + r;
      float inv = 1.0f / (Lpart[0][qr] + Lpart[1][qr] + Lpart[2][qr] + Lpart[3][qr]);
      int tg = qtile * 64 + qr;
      _Float16* op = ctx + ((size_t)(b * SEQT + tg)) * DMODEL + h * HDIM;
#pragma unroll
      for (int ntd = 0; ntd < 4; ++ntd)
        op[ntd * 16 + l15] = (_Float16)(acc[ntd][r] * inv);
    }
  }
}

// ---------------------------------------------------------------------------
// Host launch. Workspace layout (88 MB, aliased over the timeline):
//  [0,24M)   wt      : transposed f16 weights. W1^T bytes [8M,16M) are dead
//                      after the W1 GEMM -> reused as W2 split-K partial p1
//                      (rewritten by prep on the next replay).
//  [24,32M)  h16     : LN1 out -> reused as ctx16 after QKV GEMM reads it
//  [32,56M)  q,k,vt  : f16; q,k [B,H,T,HD], v transposed [B,H,HD,T]
//                      -> [32,48M) reused as x1 (fp32), [48,56M) as h2 (f16)
//  [56,88M)  mid16   : f16 [4096,4096]
// ---------------------------------------------------------------------------
extern "C" void kernel_launch(void* const* d_in, const int* in_sizes, int n_in,
                              void* d_out, int out_size, void* d_ws, size_t ws_size,
                              hipStream_t stream) {
  (void)in_sizes; (void)n_in; (void)out_size; (void)ws_size;
  const float* x    = (const float*)d_in[0];
  const float* ln1g = (const float*)d_in[1];
  const float* ln1b = (const float*)d_in[2];
  const float* Wq   = (const float*)d_in[3];
  const float* bq   = (const float*)d_in[4];
  const float* Wk   = (const float*)d_in[5];
  const float* bk   = (const float*)d_in[6];
  const float* Wv   = (const float*)d_in[7];
  const float* bv   = (const float*)d_in[8];
  const float* Wo   = (const float*)d_in[9];
  const float* bo   = (const float*)d_in[10];
  const float* ln2g = (const float*)d_in[11];
  const float* ln2b = (const float*)d_in[12];
  const float* W1   = (const float*)d_in[13];
  const float* b1   = (const float*)d_in[14];
  const float* W2   = (const float*)d_in[15];
  const float* b2   = (const float*)d_in[16];
  float* out = (float*)d_out;

  char* ws = (char*)d_ws;
  _Float16* wt    = (_Float16*)(ws);
  _Float16* h16   = (_Float16*)(ws + ((size_t)24 << 20));
  _Float16* qkv   = (_Float16*)(ws + ((size_t)32 << 20));
  _Float16* ctx16 = (_Float16*)(ws + ((size_t)24 << 20));  // reuse h16
  float*    x1    = (float*)   (ws + ((size_t)32 << 20));  // reuse q,k
  _Float16* h2    = (_Float16*)(ws + ((size_t)48 << 20));  // reuse vt
  _Float16* mid   = (_Float16*)(ws + ((size_t)56 << 20));
  _Float16* part1 = (_Float16*)(ws + ((size_t)8 << 20));   // dead W1^T region

  const size_t QKV1 = (size_t)NTOK * DMODEL;  // 4M elements per matrix

  prep_kernel<<<7168, 256, 0, stream>>>(x, ln1g, ln1b, h16,
                                        Wq, Wk, Wv, Wo, W1, W2, wt);
  // QKV: gemmw OUTMODE2, grid (32, 48) = 1536 blocks, 3 blk/CU
  gemmw_kernel<2><<<dim3(32, 48), 256, 0, stream>>>(
      h16, wt, 1024, bq, bk, bv, nullptr, nullptr, qkv);
  attn_kernel<<<dim3(16, 32), 256, 0, stream>>>(
      qkv, qkv + QKV1, qkv + 2 * QKV1, ctx16);
  // Wo: gemmw OUTMODE0
  gemmw_kernel<0><<<dim3(32, 16), 256, 0, stream>>>(
      ctx16, wt + (size_t)3 * 1024 * 1024, 1024, bo, nullptr, nullptr, x, x1, nullptr);
  ln_kernel<<<NTOK, 256, 0, stream>>>(x1, ln2g, ln2b, h2);
  // W1: gemmw OUTMODE1, grid (32, 64) = 2048 blocks, 3 blk/CU
  gemmw_kernel<1><<<dim3(32, 64), 256, 0, stream>>>(
      h2, wt + (size_t)4 * 1024 * 1024, 1024, b1, nullptr, nullptr, nullptr,
      nullptr, mid);
  // W2: gemmw OUTMODE3 split-K=2, grid (32,16,2) = 1024 blocks, 3 blk/CU
  gemmw_kernel<3><<<dim3(32, 16, 2), 256, 0, stream>>>(
      mid, wt + (size_t)8 * 1024 * 1024, 4096, b2, nullptr, nullptr, x1, out, part1);
  redux_kernel<<<4096, 256, 0, stream>>>(out, part1);
}